// Round 2
// baseline (763.616 us; speedup 1.0000x reference)
//
#include <hip/hip_runtime.h>
#include <stdint.h>

// Problem constants (from reference)
#define B 1024
#define D 512
#define NPERT 100
#define BD (B * D)              // 524288 = 2^19
#define C2 (2 * D)              // 1024 output columns
#define OUT_N (B * C2)          // 1,048,576

// ---------------- Threefry-2x32 (exact JAX implementation) ----------------
__host__ __device__ __forceinline__ uint32_t rotl32(uint32_t v, int r) {
    return (v << r) | (v >> (32 - r));
}

__host__ __device__ __forceinline__ void tf2x32(uint32_t k0, uint32_t k1,
                                                uint32_t x0, uint32_t x1,
                                                uint32_t& o0, uint32_t& o1) {
    uint32_t ks2 = k0 ^ k1 ^ 0x1BD11BDAu;
    x0 += k0; x1 += k1;
#define TF_R4(a,b,c,d_) \
    x0 += x1; x1 = rotl32(x1, a); x1 ^= x0; \
    x0 += x1; x1 = rotl32(x1, b); x1 ^= x0; \
    x0 += x1; x1 = rotl32(x1, c); x1 ^= x0; \
    x0 += x1; x1 = rotl32(x1, d_); x1 ^= x0;
    TF_R4(13, 15, 26, 6);  x0 += k1;  x1 += ks2 + 1u;
    TF_R4(17, 29, 16, 24); x0 += ks2; x1 += k0  + 2u;
    TF_R4(13, 15, 26, 6);  x0 += k0;  x1 += k1  + 3u;
    TF_R4(17, 29, 16, 24); x0 += k1;  x1 += ks2 + 4u;
    TF_R4(13, 15, 26, 6);  x0 += ks2; x1 += k0  + 5u;
#undef TF_R4
    o0 = x0; o1 = x1;
}

// Partitionable fold-like split: child i of (k0,k1) = threefry(key, (0, i)),
// child key = (out0, out1).
static void host_child(uint32_t k0, uint32_t k1, uint32_t i,
                       uint32_t& c0, uint32_t& c1) {
    tf2x32(k0, k1, 0u, i, c0, c1);
}

// Partitionable 32-bit random bits for flat index j (size < 2^32 so hi=0):
// bits = out0 ^ out1 of threefry(key, (0, j)).
__device__ __forceinline__ uint32_t pbits32(uint32_t k0, uint32_t k1, uint32_t j) {
    uint32_t b0, b1;
    tf2x32(k0, k1, 0u, j, b0, b1);
    return b0 ^ b1;
}

// ---------------- bit -> float helpers (exact JAX semantics) ----------------
__device__ __forceinline__ float u01_from_bits(uint32_t bits) {
    // bitcast((bits >> 9) | 0x3F800000) - 1.0  -> [0, 1)
    return __uint_as_float((bits >> 9) | 0x3F800000u) - 1.0f;
}

// XLA ErfInv32 (Giles single-precision polynomial)
__device__ __forceinline__ float erfinv_f32(float x) {
    float w = -log1pf(-x * x);
    float p;
    if (w < 5.0f) {
        w = w - 2.5f;
        p = 2.81022636e-08f;
        p = fmaf(p, w, 3.43273939e-07f);
        p = fmaf(p, w, -3.5233877e-06f);
        p = fmaf(p, w, -4.39150654e-06f);
        p = fmaf(p, w, 0.00021858087f);
        p = fmaf(p, w, -0.00125372503f);
        p = fmaf(p, w, -0.00417768164f);
        p = fmaf(p, w, 0.246640727f);
        p = fmaf(p, w, 1.50140941f);
    } else {
        w = sqrtf(w) - 3.0f;
        p = -0.000200214257f;
        p = fmaf(p, w, 0.000100950558f);
        p = fmaf(p, w, 0.00134934322f);
        p = fmaf(p, w, -0.00367342844f);
        p = fmaf(p, w, 0.00573950773f);
        p = fmaf(p, w, -0.0076224613f);
        p = fmaf(p, w, 0.00943887047f);
        p = fmaf(p, w, 1.00167406f);
        p = fmaf(p, w, 2.83297682f);
    }
    return p * x;
}

__device__ __forceinline__ float normal_from_bits(uint32_t bits) {
    const float lo = -0.99999994f;              // nextafter(-1,0) in f32
    float f = u01_from_bits(bits);
    float u = f * 2.0f + lo;                    // (hi-lo) rounds to 2.0f exactly
    u = fmaxf(lo, u);
    return 1.41421356f * erfinv_f32(u);         // sqrt(2) in f32
}

// ---------------- scratch (device globals: no ws_size dependency) ----------------
__device__ float g_std[2 * B];          // per-row ddof=1 std, [feat*B + b]
__device__ float g_inv[OUT_N];          // 1/var per (b, col)
__device__ float g_part[16 * C2];       // colsum partials (16 row-groups of 64)
__device__ float g_colsum[C2];          // per-column sum of 1/var

// ---------------- kernel 1: per-row std (ddof=1) ----------------
__global__ void std_kernel(const float* __restrict__ spa,
                           const float* __restrict__ spe) {
    int row = blockIdx.x;                       // 0..2047
    const float* x = (row < B) ? (spa + row * D) : (spe + (row - B) * D);
    int t = threadIdx.x;                        // 64 threads = 1 wave
    float s = 0.0f, s2 = 0.0f;
    #pragma unroll
    for (int k = 0; k < D / 64; ++k) {
        float v = x[t + 64 * k];
        s += v;
        s2 += v * v;
    }
    #pragma unroll
    for (int off = 32; off > 0; off >>= 1) {
        s  += __shfl_down(s, off);
        s2 += __shfl_down(s2, off);
    }
    if (t == 0) {
        float var = (s2 - s * s * (1.0f / (float)D)) * (1.0f / (float)(D - 1));
        g_std[row] = sqrtf(fmaxf(var, 0.0f));
    }
}

// ---------------- kernel 2: the PRNG + accumulate kernel ----------------
__global__ __launch_bounds__(256) void main_kernel(
        const float* __restrict__ spa, const float* __restrict__ spe,
        float* __restrict__ out,
        uint32_t kmA0, uint32_t kmA1, uint32_t knA0, uint32_t knA1,
        uint32_t kmB0, uint32_t kmB1, uint32_t knB0, uint32_t knB1) {
    int tid  = blockIdx.x * 256 + threadIdx.x;  // 0 .. 2*BD-1
    int feat = tid >> 19;                       // BD = 2^19
    int rem  = tid & (BD - 1);                  // b*D + d
    int b    = rem >> 9;                        // D = 2^9
    int d    = rem & (D - 1);

    uint32_t km0 = feat ? kmB0 : kmA0;
    uint32_t km1 = feat ? kmB1 : kmA1;
    uint32_t kn0 = feat ? knB0 : knA0;
    uint32_t kn1 = feat ? knB1 : knA1;

    const float* src = feat ? spe : spa;
    float x  = src[rem];
    float sd = g_std[feat * B + b];

    float T1 = 0.0f, T2 = 0.0f;
    #pragma unroll 4
    for (int p = 0; p < NPERT; ++p) {
        uint32_t j = (uint32_t)rem + (uint32_t)p * (uint32_t)BD;  // flat [P,B,D] idx
        uint32_t mb = pbits32(km0, km1, j);     // mask bits
        uint32_t nb = pbits32(kn0, kn1, j);     // normal bits
        float m = u01_from_bits(mb);
        float n = normal_from_bits(nb);
        float g = (m < 0.2f) ? n : 0.0f;
        T1 += g;
        T2 += g * g;
    }

    float S    = 100.0f * x + sd * T1;                    // sum_p candidates
    float mu   = T1 * 0.01f;
    float var  = sd * sd * (T2 * 0.01f - mu * mu) + 1e-6f; // biased var + eps
    float inv  = 1.0f / var;

    int c = (feat << 9) | d;
    int o = b * C2 + c;
    g_inv[o] = inv;
    out[o]   = inv * S;                                   // unnormalized Z
}

// ---------------- kernel 3a/3b: deterministic column sum of 1/var ----------------
__global__ void colsum_part_kernel() {
    int c = blockIdx.x * 256 + threadIdx.x;     // grid.x = 4
    int grp = blockIdx.y;                       // grid.y = 16 (64 rows each)
    const float* base = g_inv + grp * 64 * C2 + c;
    float s = 0.0f;
    #pragma unroll 4
    for (int r = 0; r < 64; ++r) s += base[r * C2];
    g_part[grp * C2 + c] = s;
}

__global__ void colsum_fin_kernel() {
    int c = blockIdx.x * 256 + threadIdx.x;     // grid.x = 4
    float s = 0.0f;
    #pragma unroll
    for (int g = 0; g < 16; ++g) s += g_part[g * C2 + c];
    g_colsum[c] = s;
}

// ---------------- kernel 4: normalize ----------------
__global__ void finalize_kernel(float* __restrict__ out) {
    int i = blockIdx.x * 256 + threadIdx.x;
    out[i] = out[i] / g_colsum[i & (C2 - 1)];
}

// ---------------- launch ----------------
extern "C" void kernel_launch(void* const* d_in, const int* in_sizes, int n_in,
                              void* d_out, int out_size, void* d_ws, size_t ws_size,
                              hipStream_t stream) {
    const float* spa = (const float*)d_in[0];
    const float* spe = (const float*)d_in[1];
    float* out = (float*)d_out;

    // key(42) -> data (0, 42). Partitionable fold-like splits:
    // k_spa = TF(root,(0,0)), k_spe = TF(root,(0,1));
    // km = TF(k,(0,0)), kn = TF(k,(0,1)).
    uint32_t spa0, spa1, spe0, spe1;
    host_child(0u, 42u, 0u, spa0, spa1);
    host_child(0u, 42u, 1u, spe0, spe1);
    uint32_t ka[4], kb[4];
    host_child(spa0, spa1, 0u, ka[0], ka[1]);   // km_spa
    host_child(spa0, spa1, 1u, ka[2], ka[3]);   // kn_spa
    host_child(spe0, spe1, 0u, kb[0], kb[1]);   // km_spe
    host_child(spe0, spe1, 1u, kb[2], kb[3]);   // kn_spe

    std_kernel<<<2 * B, 64, 0, stream>>>(spa, spe);

    main_kernel<<<(2 * BD) / 256, 256, 0, stream>>>(
        spa, spe, out,
        ka[0], ka[1], ka[2], ka[3],
        kb[0], kb[1], kb[2], kb[3]);

    dim3 pgrid(4, 16);
    colsum_part_kernel<<<pgrid, 256, 0, stream>>>();
    colsum_fin_kernel<<<4, 256, 0, stream>>>();
    finalize_kernel<<<OUT_N / 256, 256, 0, stream>>>(out);
}

// Round 3
// 540.244 us; speedup vs baseline: 1.4135x; 1.4135x over previous
//
#include <hip/hip_runtime.h>
#include <stdint.h>

// Problem constants (from reference)
#define B 1024
#define D 512
#define NPERT 100
#define BD (B * D)              // 524288 = 2^19
#define HBD (BD / 2)            // 262144
#define C2 (2 * D)              // 1024 output columns
#define OUT_N (B * C2)          // 1,048,576

// mask threshold: u01(bits) < 0.2f  <=>  bits < 0x33333E00  (exact)
#define MASK_THR 858993664u

// ---------------- Threefry-2x32 (exact JAX implementation) ----------------
__host__ __device__ __forceinline__ uint32_t rotl32(uint32_t v, int r) {
    return (v << r) | (v >> (32 - r));
}

__host__ __device__ __forceinline__ void tf2x32(uint32_t k0, uint32_t k1,
                                                uint32_t x0, uint32_t x1,
                                                uint32_t& o0, uint32_t& o1) {
    uint32_t ks2 = k0 ^ k1 ^ 0x1BD11BDAu;
    x0 += k0; x1 += k1;
#define TF_R4(a,b,c,d_) \
    x0 += x1; x1 = rotl32(x1, a); x1 ^= x0; \
    x0 += x1; x1 = rotl32(x1, b); x1 ^= x0; \
    x0 += x1; x1 = rotl32(x1, c); x1 ^= x0; \
    x0 += x1; x1 = rotl32(x1, d_); x1 ^= x0;
    TF_R4(13, 15, 26, 6);  x0 += k1;  x1 += ks2 + 1u;
    TF_R4(17, 29, 16, 24); x0 += ks2; x1 += k0  + 2u;
    TF_R4(13, 15, 26, 6);  x0 += k0;  x1 += k1  + 3u;
    TF_R4(17, 29, 16, 24); x0 += k1;  x1 += ks2 + 4u;
    TF_R4(13, 15, 26, 6);  x0 += ks2; x1 += k0  + 5u;
#undef TF_R4
    o0 = x0; o1 = x1;
}

// Partitionable fold-like split: child i = threefry(key, (0, i))
static void host_child(uint32_t k0, uint32_t k1, uint32_t i,
                       uint32_t& c0, uint32_t& c1) {
    tf2x32(k0, k1, 0u, i, c0, c1);
}

// Partitionable 32-bit random bits for flat index j: xor of both output words.
__device__ __forceinline__ uint32_t pbits32(uint32_t k0, uint32_t k1, uint32_t j) {
    uint32_t b0, b1;
    tf2x32(k0, k1, 0u, j, b0, b1);
    return b0 ^ b1;
}

// ---------------- bit -> float helpers ----------------
__device__ __forceinline__ float u01_from_bits(uint32_t bits) {
    return __uint_as_float((bits >> 9) | 0x3F800000u) - 1.0f;
}

// Giles erfinv polynomial, with cheap w = -ln(1-x^2) via v_log_f32.
// (fma keeps 1-x^2 accurate; normals only need ~1e-2 abs accuracy here.)
__device__ __forceinline__ float erfinv_fast(float x) {
    float w = -__logf(fmaf(-x, x, 1.0f));
    float p;
    if (__builtin_expect(w >= 5.0f, 0)) {
        float s = sqrtf(w) - 3.0f;
        p = -0.000200214257f;
        p = fmaf(p, s, 0.000100950558f);
        p = fmaf(p, s, 0.00134934322f);
        p = fmaf(p, s, -0.00367342844f);
        p = fmaf(p, s, 0.00573950773f);
        p = fmaf(p, s, -0.0076224613f);
        p = fmaf(p, s, 0.00943887047f);
        p = fmaf(p, s, 1.00167406f);
        p = fmaf(p, s, 2.83297682f);
    } else {
        float t = w - 2.5f;
        p = 2.81022636e-08f;
        p = fmaf(p, t, 3.43273939e-07f);
        p = fmaf(p, t, -3.5233877e-06f);
        p = fmaf(p, t, -4.39150654e-06f);
        p = fmaf(p, t, 0.00021858087f);
        p = fmaf(p, t, -0.00125372503f);
        p = fmaf(p, t, -0.00417768164f);
        p = fmaf(p, t, 0.246640727f);
        p = fmaf(p, t, 1.50140941f);
    }
    return p * x;
}

__device__ __forceinline__ float normal_from_bits(uint32_t bits) {
    const float lo = -0.99999994f;              // nextafter(-1,0) in f32
    float f = u01_from_bits(bits);
    float u = f * 2.0f + lo;
    u = fmaxf(lo, u);
    return 1.41421356f * erfinv_fast(u);
}

// ---------------- scratch (device globals) ----------------
__device__ float g_std[2 * B];
__device__ float g_inv[OUT_N];
__device__ float g_part[16 * C2];
__device__ float g_colsum[C2];

// ---------------- kernel 1: per-row std (ddof=1) ----------------
__global__ void std_kernel(const float* __restrict__ spa,
                           const float* __restrict__ spe) {
    int row = blockIdx.x;                       // 0..2047
    const float* x = (row < B) ? (spa + row * D) : (spe + (row - B) * D);
    int t = threadIdx.x;                        // 64 threads = 1 wave
    float s = 0.0f, s2 = 0.0f;
    #pragma unroll
    for (int k = 0; k < D / 64; ++k) {
        float v = x[t + 64 * k];
        s += v;
        s2 += v * v;
    }
    #pragma unroll
    for (int off = 32; off > 0; off >>= 1) {
        s  += __shfl_down(s, off);
        s2 += __shfl_down(s2, off);
    }
    if (t == 0) {
        float var = (s2 - s * s * (1.0f / (float)D)) * (1.0f / (float)(D - 1));
        g_std[row] = sqrtf(fmaxf(var, 0.0f));
    }
}

// ---------------- kernel 2: PRNG + accumulate, 2 elements/thread ----------------
__global__ __launch_bounds__(256) void main_kernel(
        const float* __restrict__ spa, const float* __restrict__ spe,
        float* __restrict__ out,
        uint32_t kmA0, uint32_t kmA1, uint32_t knA0, uint32_t knA1,
        uint32_t kmB0, uint32_t kmB1, uint32_t knB0, uint32_t knB1) {
    // grid.x = 2048: blocks [0,1024) -> feat 0, [1024,2048) -> feat 1.
    // Each thread handles rem and rem + HBD (same feat -> wave-uniform keys).
    int feat = (int)(blockIdx.x >> 10);                    // scalar
    int idx  = (int)((blockIdx.x & 1023u) * 256u + threadIdx.x);
    int rem1 = idx;                                        // b*D + d, first half
    int rem2 = idx + HBD;                                  // second half

    uint32_t km0 = feat ? kmB0 : kmA0;                     // scalar selects
    uint32_t km1 = feat ? kmB1 : kmA1;
    uint32_t kn0 = feat ? knB0 : knA0;
    uint32_t kn1 = feat ? knB1 : knA1;

    const float* src = feat ? spe : spa;
    float x1 = src[rem1];
    float x2 = src[rem2];
    float sd1 = g_std[feat * B + (rem1 >> 9)];
    float sd2 = g_std[feat * B + (rem2 >> 9)];

    uint32_t j1 = (uint32_t)rem1;
    uint32_t j2 = (uint32_t)rem2;
    float T1a = 0.0f, T2a = 0.0f, T1b = 0.0f, T2b = 0.0f;

    #pragma unroll 2
    for (int p = 0; p < NPERT; ++p) {
        uint32_t mb1 = pbits32(km0, km1, j1);   // 4 independent threefry chains
        uint32_t nb1 = pbits32(kn0, kn1, j1);
        uint32_t mb2 = pbits32(km0, km1, j2);
        uint32_t nb2 = pbits32(kn0, kn1, j2);
        float n1 = normal_from_bits(nb1);
        float n2 = normal_from_bits(nb2);
        float g1 = (mb1 < MASK_THR) ? n1 : 0.0f;
        float g2 = (mb2 < MASK_THR) ? n2 : 0.0f;
        T1a += g1; T2a = fmaf(g1, g1, T2a);
        T1b += g2; T2b = fmaf(g2, g2, T2b);
        j1 += BD; j2 += BD;
    }

    {   // element 1
        float S   = 100.0f * x1 + sd1 * T1a;
        float mu  = T1a * 0.01f;
        float var = sd1 * sd1 * (T2a * 0.01f - mu * mu) + 1e-6f;
        float inv = 1.0f / var;
        int c = (feat << 9) | (rem1 & (D - 1));
        int o = (rem1 >> 9) * C2 + c;
        g_inv[o] = inv;
        out[o]   = inv * S;
    }
    {   // element 2
        float S   = 100.0f * x2 + sd2 * T1b;
        float mu  = T1b * 0.01f;
        float var = sd2 * sd2 * (T2b * 0.01f - mu * mu) + 1e-6f;
        float inv = 1.0f / var;
        int c = (feat << 9) | (rem2 & (D - 1));
        int o = (rem2 >> 9) * C2 + c;
        g_inv[o] = inv;
        out[o]   = inv * S;
    }
}

// ---------------- kernel 3a/3b: deterministic column sum of 1/var ----------------
__global__ void colsum_part_kernel() {
    int c = blockIdx.x * 256 + threadIdx.x;     // grid.x = 4
    int grp = blockIdx.y;                       // grid.y = 16 (64 rows each)
    const float* base = g_inv + grp * 64 * C2 + c;
    float s = 0.0f;
    #pragma unroll 4
    for (int r = 0; r < 64; ++r) s += base[r * C2];
    g_part[grp * C2 + c] = s;
}

__global__ void colsum_fin_kernel() {
    int c = blockIdx.x * 256 + threadIdx.x;     // grid.x = 4
    float s = 0.0f;
    #pragma unroll
    for (int g = 0; g < 16; ++g) s += g_part[g * C2 + c];
    g_colsum[c] = s;
}

// ---------------- kernel 4: normalize ----------------
__global__ void finalize_kernel(float* __restrict__ out) {
    int i = blockIdx.x * 256 + threadIdx.x;
    out[i] = out[i] / g_colsum[i & (C2 - 1)];
}

// ---------------- launch ----------------
extern "C" void kernel_launch(void* const* d_in, const int* in_sizes, int n_in,
                              void* d_out, int out_size, void* d_ws, size_t ws_size,
                              hipStream_t stream) {
    const float* spa = (const float*)d_in[0];
    const float* spe = (const float*)d_in[1];
    float* out = (float*)d_out;

    // key(42) -> (0,42); partitionable fold-like splits.
    uint32_t spa0, spa1, spe0, spe1;
    host_child(0u, 42u, 0u, spa0, spa1);
    host_child(0u, 42u, 1u, spe0, spe1);
    uint32_t ka[4], kb[4];
    host_child(spa0, spa1, 0u, ka[0], ka[1]);   // km_spa
    host_child(spa0, spa1, 1u, ka[2], ka[3]);   // kn_spa
    host_child(spe0, spe1, 0u, kb[0], kb[1]);   // km_spe
    host_child(spe0, spe1, 1u, kb[2], kb[3]);   // kn_spe

    std_kernel<<<2 * B, 64, 0, stream>>>(spa, spe);

    main_kernel<<<2048, 256, 0, stream>>>(
        spa, spe, out,
        ka[0], ka[1], ka[2], ka[3],
        kb[0], kb[1], kb[2], kb[3]);

    dim3 pgrid(4, 16);
    colsum_part_kernel<<<pgrid, 256, 0, stream>>>();
    colsum_fin_kernel<<<4, 256, 0, stream>>>();
    finalize_kernel<<<OUT_N / 256, 256, 0, stream>>>(out);
}

// Round 4
// 413.088 us; speedup vs baseline: 1.8486x; 1.3078x over previous
//
#include <hip/hip_runtime.h>
#include <stdint.h>

// Problem constants (from reference)
#define B 1024
#define D 512
#define NPERT 100
#define BD (B * D)              // 524288 = 2^19
#define QBD (BD / 4)            // 131072 = 2^17
#define C2 (2 * D)              // 1024 output columns
#define OUT_N (B * C2)          // 1,048,576

// mask threshold: u01(bits) < 0.2f  <=>  bits < 0x33333E00  (exact)
#define MASK_THR 858993664u

// ---------------- Threefry-2x32 (exact JAX implementation) ----------------
__host__ __device__ __forceinline__ uint32_t rotl32(uint32_t v, int r) {
    return (v << r) | (v >> (32 - r));
}

__host__ __device__ __forceinline__ void tf2x32(uint32_t k0, uint32_t k1,
                                                uint32_t x0, uint32_t x1,
                                                uint32_t& o0, uint32_t& o1) {
    uint32_t ks2 = k0 ^ k1 ^ 0x1BD11BDAu;
    x0 += k0; x1 += k1;
#define TF_R4(a,b,c,d_) \
    x0 += x1; x1 = rotl32(x1, a); x1 ^= x0; \
    x0 += x1; x1 = rotl32(x1, b); x1 ^= x0; \
    x0 += x1; x1 = rotl32(x1, c); x1 ^= x0; \
    x0 += x1; x1 = rotl32(x1, d_); x1 ^= x0;
    TF_R4(13, 15, 26, 6);  x0 += k1;  x1 += ks2 + 1u;
    TF_R4(17, 29, 16, 24); x0 += ks2; x1 += k0  + 2u;
    TF_R4(13, 15, 26, 6);  x0 += k0;  x1 += k1  + 3u;
    TF_R4(17, 29, 16, 24); x0 += k1;  x1 += ks2 + 4u;
    TF_R4(13, 15, 26, 6);  x0 += ks2; x1 += k0  + 5u;
#undef TF_R4
    o0 = x0; o1 = x1;
}

// Partitionable fold-like split: child i = threefry(key, (0, i))
static void host_child(uint32_t k0, uint32_t k1, uint32_t i,
                       uint32_t& c0, uint32_t& c1) {
    tf2x32(k0, k1, 0u, i, c0, c1);
}

// Partitionable 32-bit random bits for flat index j: xor of both output words.
__device__ __forceinline__ uint32_t pbits32(uint32_t k0, uint32_t k1, uint32_t j) {
    uint32_t b0, b1;
    tf2x32(k0, k1, 0u, j, b0, b1);
    return b0 ^ b1;
}

// ---------------- normal draw (sqrt(2) pre-folded into coefficients) ----------------
// n = sqrt2 * erfinv(u), u = u01(bits)*2 + nextafter(-1,0); fmax clamp is
// provably redundant (u in [-0.99999994, 1-2^-22+2^-24]).
__device__ __forceinline__ float normal_from_bits(uint32_t bits) {
    const float lo = -0.99999994f;
    float f = __uint_as_float((bits >> 9) | 0x3F800000u) - 1.0f;
    float u = fmaf(f, 2.0f, lo);
    // w = -ln(1 - u^2); v_log_f32 gives log2 -> scale by -ln2
    float w = -0.69314718f * __builtin_amdgcn_logf(fmaf(-u, u, 1.0f));
    float p;
    if (__builtin_expect(w >= 5.0f, 0)) {
        float s = sqrtf(w) - 3.0f;
        p = -0.00028314702f;
        p = fmaf(p, s, 0.00014276567f);
        p = fmaf(p, s, 0.0019082633f);
        p = fmaf(p, s, -0.0051950082f);
        p = fmaf(p, s, 0.0081169485f);
        p = fmaf(p, s, -0.010779902f);
        p = fmaf(p, s, 0.013348609f);
        p = fmaf(p, s, 1.4165813f);
        p = fmaf(p, s, 4.0064936f);
    } else {
        float t = w - 2.5f;
        p = 3.9742444e-08f;
        p = fmaf(p, t, 4.8546906e-07f);
        p = fmaf(p, t, -4.9828437e-06f);
        p = fmaf(p, t, -6.2105324e-06f);
        p = fmaf(p, t, 0.00030912052f);
        p = fmaf(p, t, -0.0017730336f);
        p = fmaf(p, t, -0.0059081636f);
        p = fmaf(p, t, 0.34880054f);
        p = fmaf(p, t, 2.1233180f);
    }
    return p * u;
}

// ---------------- scratch (device globals) ----------------
__device__ float g_std[2 * B];
__device__ float g_inv[OUT_N];
__device__ float g_part[16 * C2];
__device__ float g_colsum[C2];

// ---------------- kernel 1: per-row std (ddof=1) ----------------
__global__ void std_kernel(const float* __restrict__ spa,
                           const float* __restrict__ spe) {
    int row = blockIdx.x;                       // 0..2047
    const float* x = (row < B) ? (spa + row * D) : (spe + (row - B) * D);
    int t = threadIdx.x;                        // 64 threads = 1 wave
    float s = 0.0f, s2 = 0.0f;
    #pragma unroll
    for (int k = 0; k < D / 64; ++k) {
        float v = x[t + 64 * k];
        s += v;
        s2 += v * v;
    }
    #pragma unroll
    for (int off = 32; off > 0; off >>= 1) {
        s  += __shfl_down(s, off);
        s2 += __shfl_down(s2, off);
    }
    if (t == 0) {
        float var = (s2 - s * s * (1.0f / (float)D)) * (1.0f / (float)(D - 1));
        g_std[row] = sqrtf(fmaxf(var, 0.0f));
    }
}

// ---------------- kernel 2: PRNG + accumulate, 4 elements/thread ----------------
__global__ __launch_bounds__(256) void main_kernel(
        const float* __restrict__ spa, const float* __restrict__ spe,
        float* __restrict__ out,
        uint32_t kmA0, uint32_t kmA1, uint32_t knA0, uint32_t knA1,
        uint32_t kmB0, uint32_t kmB1, uint32_t knB0, uint32_t knB1) {
    // grid.x = 1024: blocks [0,512) -> feat 0, [512,1024) -> feat 1 (scalar).
    // Each thread handles idx + e*QBD, e = 0..3 (same feat -> SGPR keys).
    int feat = (int)(blockIdx.x >> 9);
    int idx  = (int)((blockIdx.x & 511u) * 256u + threadIdx.x);   // [0, QBD)

    uint32_t km0 = feat ? kmB0 : kmA0;
    uint32_t km1 = feat ? kmB1 : kmA1;
    uint32_t kn0 = feat ? knB0 : knA0;
    uint32_t kn1 = feat ? knB1 : knA1;

    const float* src = feat ? spe : spa;

    float x[4], sd[4], T1[4], T2[4];
    uint32_t j[4];
    #pragma unroll
    for (int e = 0; e < 4; ++e) {
        int rem = idx + e * QBD;
        x[e]  = src[rem];
        sd[e] = g_std[feat * B + (rem >> 9)];
        j[e]  = (uint32_t)rem;
        T1[e] = 0.0f;
        T2[e] = 0.0f;
    }

    #pragma unroll 1
    for (int p = 0; p < NPERT; ++p) {
        uint32_t mb[4], nb[4];
        #pragma unroll
        for (int e = 0; e < 4; ++e) {
            mb[e] = pbits32(km0, km1, j[e]);    // 8 independent threefry chains
            nb[e] = pbits32(kn0, kn1, j[e]);
            j[e] += BD;
        }
        #pragma unroll
        for (int e = 0; e < 4; ++e) {
            float n = normal_from_bits(nb[e]);
            float g = (mb[e] < MASK_THR) ? n : 0.0f;
            T1[e] += g;
            T2[e] = fmaf(g, g, T2[e]);
        }
    }

    #pragma unroll
    for (int e = 0; e < 4; ++e) {
        int rem = idx + e * QBD;
        float S   = 100.0f * x[e] + sd[e] * T1[e];
        float mu  = T1[e] * 0.01f;
        float var = sd[e] * sd[e] * (T2[e] * 0.01f - mu * mu) + 1e-6f;
        float inv = 1.0f / var;
        int c = (feat << 9) | (rem & (D - 1));
        int o = (rem >> 9) * C2 + c;
        g_inv[o] = inv;
        out[o]   = inv * S;
    }
}

// ---------------- kernel 3a/3b: deterministic column sum of 1/var ----------------
__global__ void colsum_part_kernel() {
    int c = blockIdx.x * 256 + threadIdx.x;     // grid.x = 4
    int grp = blockIdx.y;                       // grid.y = 16 (64 rows each)
    const float* base = g_inv + grp * 64 * C2 + c;
    float s = 0.0f;
    #pragma unroll 4
    for (int r = 0; r < 64; ++r) s += base[r * C2];
    g_part[grp * C2 + c] = s;
}

__global__ void colsum_fin_kernel() {
    int c = blockIdx.x * 256 + threadIdx.x;     // grid.x = 4
    float s = 0.0f;
    #pragma unroll
    for (int g = 0; g < 16; ++g) s += g_part[g * C2 + c];
    g_colsum[c] = s;
}

// ---------------- kernel 4: normalize ----------------
__global__ void finalize_kernel(float* __restrict__ out) {
    int i = blockIdx.x * 256 + threadIdx.x;
    out[i] = out[i] / g_colsum[i & (C2 - 1)];
}

// ---------------- launch ----------------
extern "C" void kernel_launch(void* const* d_in, const int* in_sizes, int n_in,
                              void* d_out, int out_size, void* d_ws, size_t ws_size,
                              hipStream_t stream) {
    const float* spa = (const float*)d_in[0];
    const float* spe = (const float*)d_in[1];
    float* out = (float*)d_out;

    // key(42) -> (0,42); partitionable fold-like splits.
    uint32_t spa0, spa1, spe0, spe1;
    host_child(0u, 42u, 0u, spa0, spa1);
    host_child(0u, 42u, 1u, spe0, spe1);
    uint32_t ka[4], kb[4];
    host_child(spa0, spa1, 0u, ka[0], ka[1]);   // km_spa
    host_child(spa0, spa1, 1u, ka[2], ka[3]);   // kn_spa
    host_child(spe0, spe1, 0u, kb[0], kb[1]);   // km_spe
    host_child(spe0, spe1, 1u, kb[2], kb[3]);   // kn_spe

    std_kernel<<<2 * B, 64, 0, stream>>>(spa, spe);

    main_kernel<<<1024, 256, 0, stream>>>(
        spa, spe, out,
        ka[0], ka[1], ka[2], ka[3],
        kb[0], kb[1], kb[2], kb[3]);

    dim3 pgrid(4, 16);
    colsum_part_kernel<<<pgrid, 256, 0, stream>>>();
    colsum_fin_kernel<<<4, 256, 0, stream>>>();
    finalize_kernel<<<OUT_N / 256, 256, 0, stream>>>(out);
}

// Round 5
// 404.306 us; speedup vs baseline: 1.8887x; 1.0217x over previous
//
#include <hip/hip_runtime.h>
#include <stdint.h>

// Problem constants (from reference)
#define B 1024
#define D 512
#define NPERT 100
#define BD (B * D)              // 524288 = 2^19
#define QBD (BD / 4)            // 131072 = 2^17
#define C2 (2 * D)              // 1024 output columns
#define OUT_N (B * C2)          // 1,048,576

// mask threshold: u01(bits) < 0.2f  <=>  bits < 0x33333E00  (exact)
#define MASK_THR 858993664u

// ---------------- Threefry-2x32 (exact JAX implementation) ----------------
__host__ __device__ __forceinline__ uint32_t rotl32(uint32_t v, int r) {
    return (v << r) | (v >> (32 - r));
}

__host__ __device__ __forceinline__ void tf2x32(uint32_t k0, uint32_t k1,
                                                uint32_t x0, uint32_t x1,
                                                uint32_t& o0, uint32_t& o1) {
    uint32_t ks2 = k0 ^ k1 ^ 0x1BD11BDAu;
    x0 += k0; x1 += k1;
#define TF_R4(a,b,c,d_) \
    x0 += x1; x1 = rotl32(x1, a); x1 ^= x0; \
    x0 += x1; x1 = rotl32(x1, b); x1 ^= x0; \
    x0 += x1; x1 = rotl32(x1, c); x1 ^= x0; \
    x0 += x1; x1 = rotl32(x1, d_); x1 ^= x0;
    TF_R4(13, 15, 26, 6);  x0 += k1;  x1 += ks2 + 1u;
    TF_R4(17, 29, 16, 24); x0 += ks2; x1 += k0  + 2u;
    TF_R4(13, 15, 26, 6);  x0 += k0;  x1 += k1  + 3u;
    TF_R4(17, 29, 16, 24); x0 += k1;  x1 += ks2 + 4u;
    TF_R4(13, 15, 26, 6);  x0 += ks2; x1 += k0  + 5u;
#undef TF_R4
    o0 = x0; o1 = x1;
}

// Partitionable fold-like split: child i = threefry(key, (0, i))
static void host_child(uint32_t k0, uint32_t k1, uint32_t i,
                       uint32_t& c0, uint32_t& c1) {
    tf2x32(k0, k1, 0u, i, c0, c1);
}

// Partitionable 32-bit random bits for flat index j: xor of both output words.
__device__ __forceinline__ uint32_t pbits32(uint32_t k0, uint32_t k1, uint32_t j) {
    uint32_t b0, b1;
    tf2x32(k0, k1, 0u, j, b0, b1);
    return b0 ^ b1;
}

// ---------------- normal draw (sqrt(2) folded into coefficients) ----------------
__device__ __forceinline__ float normal_from_bits(uint32_t bits) {
    const float lo = -0.99999994f;
    float f = __uint_as_float((bits >> 9) | 0x3F800000u) - 1.0f;
    float u = fmaf(f, 2.0f, lo);
    float w = -0.69314718f * __builtin_amdgcn_logf(fmaf(-u, u, 1.0f));
    float p;
    if (__builtin_expect(w >= 5.0f, 0)) {
        float s = sqrtf(w) - 3.0f;
        p = -0.00028314702f;
        p = fmaf(p, s, 0.00014276567f);
        p = fmaf(p, s, 0.0019082633f);
        p = fmaf(p, s, -0.0051950082f);
        p = fmaf(p, s, 0.0081169485f);
        p = fmaf(p, s, -0.010779902f);
        p = fmaf(p, s, 0.013348609f);
        p = fmaf(p, s, 1.4165813f);
        p = fmaf(p, s, 4.0064936f);
    } else {
        float t = w - 2.5f;
        p = 3.9742444e-08f;
        p = fmaf(p, t, 4.8546906e-07f);
        p = fmaf(p, t, -4.9828437e-06f);
        p = fmaf(p, t, -6.2105324e-06f);
        p = fmaf(p, t, 0.00030912052f);
        p = fmaf(p, t, -0.0017730336f);
        p = fmaf(p, t, -0.0059081636f);
        p = fmaf(p, t, 0.34880054f);
        p = fmaf(p, t, 2.1233180f);
    }
    return p * u;
}

// ---------------- scratch (device globals) ----------------
__device__ float g_std[2 * B];
__device__ float2 g_pp[2][2 * BD];      // per-half (T1,T2) partials, 16.8 MB
__device__ float g_inv[OUT_N];
__device__ float g_part[16 * C2];
__device__ float g_colsum[C2];

// ---------------- kernel 1: per-row std (ddof=1) ----------------
__global__ void std_kernel(const float* __restrict__ spa,
                           const float* __restrict__ spe) {
    int row = blockIdx.x;                       // 0..2047
    const float* x = (row < B) ? (spa + row * D) : (spe + (row - B) * D);
    int t = threadIdx.x;                        // 64 threads = 1 wave
    float s = 0.0f, s2 = 0.0f;
    #pragma unroll
    for (int k = 0; k < D / 64; ++k) {
        float v = x[t + 64 * k];
        s += v;
        s2 += v * v;
    }
    #pragma unroll
    for (int off = 32; off > 0; off >>= 1) {
        s  += __shfl_down(s, off);
        s2 += __shfl_down(s2, off);
    }
    if (t == 0) {
        float var = (s2 - s * s * (1.0f / (float)D)) * (1.0f / (float)(D - 1));
        g_std[row] = sqrtf(fmaxf(var, 0.0f));
    }
}

// ---------------- kernel 2: pure PRNG, 4 elems/thread, p-halved ----------------
__global__ __launch_bounds__(256) void main_kernel(
        uint32_t kmA0, uint32_t kmA1, uint32_t knA0, uint32_t knA1,
        uint32_t kmB0, uint32_t kmB1, uint32_t knB0, uint32_t knB1) {
    // grid.x = 2048. bit10: feat, bit9: p-half, low 9 bits: idx block.
    int feat = (int)(blockIdx.x >> 10);                       // scalar
    int half = (int)((blockIdx.x >> 9) & 1u);                 // scalar
    int idx  = (int)((blockIdx.x & 511u) * 256u + threadIdx.x);  // [0, QBD)

    uint32_t km0 = feat ? kmB0 : kmA0;
    uint32_t km1 = feat ? kmB1 : kmA1;
    uint32_t kn0 = feat ? knB0 : knA0;
    uint32_t kn1 = feat ? knB1 : knA1;

    uint32_t jbase = (uint32_t)idx + (uint32_t)half * (NPERT / 2) * BD;
    float T1[4], T2[4];
    uint32_t j[4];
    #pragma unroll
    for (int e = 0; e < 4; ++e) {
        j[e]  = jbase + e * QBD;
        T1[e] = 0.0f;
        T2[e] = 0.0f;
    }

    #pragma unroll 1
    for (int p = 0; p < NPERT / 2; ++p) {
        uint32_t mb[4], nb[4];
        #pragma unroll
        for (int e = 0; e < 4; ++e) {
            mb[e] = pbits32(km0, km1, j[e]);    // 8 independent threefry chains
            nb[e] = pbits32(kn0, kn1, j[e]);
            j[e] += BD;
        }
        #pragma unroll
        for (int e = 0; e < 4; ++e) {
            float n = normal_from_bits(nb[e]);
            float g = (mb[e] < MASK_THR) ? n : 0.0f;
            T1[e] += g;
            T2[e] = fmaf(g, g, T2[e]);
        }
    }

    #pragma unroll
    for (int e = 0; e < 4; ++e) {
        g_pp[half][feat * BD + idx + e * QBD] = make_float2(T1[e], T2[e]);
    }
}

// ---------------- kernel 2b: combine halves + epilogue ----------------
__global__ void combine_kernel(const float* __restrict__ spa,
                               const float* __restrict__ spe,
                               float* __restrict__ out) {
    int elem = blockIdx.x * 256 + threadIdx.x;  // [0, 2*BD)
    int feat = elem >> 19;
    int rem  = elem & (BD - 1);
    float2 pa = g_pp[0][elem];
    float2 pb = g_pp[1][elem];
    float T1 = pa.x + pb.x;
    float T2 = pa.y + pb.y;
    const float* src = feat ? spe : spa;
    float x  = src[rem];
    float sd = g_std[feat * B + (rem >> 9)];
    float S   = 100.0f * x + sd * T1;
    float mu  = T1 * 0.01f;
    float var = sd * sd * (T2 * 0.01f - mu * mu) + 1e-6f;
    float inv = 1.0f / var;
    int o = (rem >> 9) * C2 + ((feat << 9) | (rem & (D - 1)));
    g_inv[o] = inv;
    out[o]   = inv * S;
}

// ---------------- kernel 3a/3b: deterministic column sum of 1/var ----------------
__global__ void colsum_part_kernel() {
    int c = blockIdx.x * 256 + threadIdx.x;     // grid.x = 4
    int grp = blockIdx.y;                       // grid.y = 16 (64 rows each)
    const float* base = g_inv + grp * 64 * C2 + c;
    float s = 0.0f;
    #pragma unroll 4
    for (int r = 0; r < 64; ++r) s += base[r * C2];
    g_part[grp * C2 + c] = s;
}

__global__ void colsum_fin_kernel() {
    int c = blockIdx.x * 256 + threadIdx.x;     // grid.x = 4
    float s = 0.0f;
    #pragma unroll
    for (int g = 0; g < 16; ++g) s += g_part[g * C2 + c];
    g_colsum[c] = s;
}

// ---------------- kernel 4: normalize ----------------
__global__ void finalize_kernel(float* __restrict__ out) {
    int i = blockIdx.x * 256 + threadIdx.x;
    out[i] = out[i] / g_colsum[i & (C2 - 1)];
}

// ---------------- launch ----------------
extern "C" void kernel_launch(void* const* d_in, const int* in_sizes, int n_in,
                              void* d_out, int out_size, void* d_ws, size_t ws_size,
                              hipStream_t stream) {
    const float* spa = (const float*)d_in[0];
    const float* spe = (const float*)d_in[1];
    float* out = (float*)d_out;

    // key(42) -> (0,42); partitionable fold-like splits.
    uint32_t spa0, spa1, spe0, spe1;
    host_child(0u, 42u, 0u, spa0, spa1);
    host_child(0u, 42u, 1u, spe0, spe1);
    uint32_t ka[4], kb[4];
    host_child(spa0, spa1, 0u, ka[0], ka[1]);   // km_spa
    host_child(spa0, spa1, 1u, ka[2], ka[3]);   // kn_spa
    host_child(spe0, spe1, 0u, kb[0], kb[1]);   // km_spe
    host_child(spe0, spe1, 1u, kb[2], kb[3]);   // kn_spe

    std_kernel<<<2 * B, 64, 0, stream>>>(spa, spe);

    main_kernel<<<2048, 256, 0, stream>>>(
        ka[0], ka[1], ka[2], ka[3],
        kb[0], kb[1], kb[2], kb[3]);

    combine_kernel<<<(2 * BD) / 256, 256, 0, stream>>>(spa, spe, out);

    dim3 pgrid(4, 16);
    colsum_part_kernel<<<pgrid, 256, 0, stream>>>();
    colsum_fin_kernel<<<4, 256, 0, stream>>>();
    finalize_kernel<<<OUT_N / 256, 256, 0, stream>>>(out);
}

// Round 6
// 404.098 us; speedup vs baseline: 1.8897x; 1.0005x over previous
//
#include <hip/hip_runtime.h>
#include <stdint.h>

// Problem constants (from reference)
#define B 1024
#define D 512
#define NPERT 100
#define BD (B * D)              // 524288 = 2^19
#define QBD (BD / 4)            // 131072 = 2^17
#define C2 (2 * D)              // 1024 output columns
#define OUT_N (B * C2)          // 1,048,576

// mask threshold: u01(bits) < 0.2f  <=>  bits < 0x33333E00  (exact)
#define MASK_THR 858993664u

// ---------------- Threefry-2x32 (exact JAX implementation) ----------------
__host__ __device__ __forceinline__ uint32_t rotl32(uint32_t v, int r) {
    return (v << r) | (v >> (32 - r));
}

__host__ __device__ __forceinline__ void tf2x32(uint32_t k0, uint32_t k1,
                                                uint32_t x0, uint32_t x1,
                                                uint32_t& o0, uint32_t& o1) {
    uint32_t ks2 = k0 ^ k1 ^ 0x1BD11BDAu;
    x0 += k0; x1 += k1;
#define TF_R4(a,b,c,d_) \
    x0 += x1; x1 = rotl32(x1, a); x1 ^= x0; \
    x0 += x1; x1 = rotl32(x1, b); x1 ^= x0; \
    x0 += x1; x1 = rotl32(x1, c); x1 ^= x0; \
    x0 += x1; x1 = rotl32(x1, d_); x1 ^= x0;
    TF_R4(13, 15, 26, 6);  x0 += k1;  x1 += ks2 + 1u;
    TF_R4(17, 29, 16, 24); x0 += ks2; x1 += k0  + 2u;
    TF_R4(13, 15, 26, 6);  x0 += k0;  x1 += k1  + 3u;
    TF_R4(17, 29, 16, 24); x0 += k1;  x1 += ks2 + 4u;
    TF_R4(13, 15, 26, 6);  x0 += ks2; x1 += k0  + 5u;
#undef TF_R4
    o0 = x0; o1 = x1;
}

// Partitionable fold-like split: child i = threefry(key, (0, i))
static void host_child(uint32_t k0, uint32_t k1, uint32_t i,
                       uint32_t& c0, uint32_t& c1) {
    tf2x32(k0, k1, 0u, i, c0, c1);
}

// Partitionable 32-bit random bits for flat index j: xor of both output words.
__device__ __forceinline__ uint32_t pbits32(uint32_t k0, uint32_t k1, uint32_t j) {
    uint32_t b0, b1;
    tf2x32(k0, k1, 0u, j, b0, b1);
    return b0 ^ b1;
}

// ---------------- normal draw ----------------
// n = sqrt2*erfinv(u) with sqrt2 folded into coefficients; polynomials
// truncated deg8->deg6 (err <= 4.3e-4, budget ~1e-3 per sensitivity calc);
// branch + Horner parameter derived directly from L = log2(1-u^2).
__device__ __forceinline__ float normal_from_bits(uint32_t bits) {
    float f = __uint_as_float((bits >> 9) | 0x3F800000u) - 1.0f;  // [0,1)
    float u = fmaf(f, 2.0f, -0.99999994f);        // [-0.99999994, 0.99999994]
    float L = __builtin_amdgcn_logf(fmaf(-u, u, 1.0f));   // log2(1-u^2) in [-23, 0]
    float p;
    if (__builtin_expect(L <= -7.2134752f, 0)) {  // w = -ln2*L >= 5 (rare)
        float w = -0.69314718f * L;
        float s = sqrtf(w) - 3.0f;
        p = 0.0019082633f;
        p = fmaf(p, s, -0.0051950082f);
        p = fmaf(p, s, 0.0081169485f);
        p = fmaf(p, s, -0.010779902f);
        p = fmaf(p, s, 0.013348609f);
        p = fmaf(p, s, 1.4165813f);
        p = fmaf(p, s, 4.0064936f);
    } else {
        float t = fmaf(L, -0.69314718f, -2.5f);   // w - 2.5 in one fma
        p = -4.9828437e-06f;
        p = fmaf(p, t, -6.2105324e-06f);
        p = fmaf(p, t, 0.00030912052f);
        p = fmaf(p, t, -0.0017730336f);
        p = fmaf(p, t, -0.0059081636f);
        p = fmaf(p, t, 0.34880054f);
        p = fmaf(p, t, 2.1233180f);
    }
    return p * u;
}

// ---------------- scratch (device globals) ----------------
__device__ float g_std[2 * B];
__device__ float2 g_pp[2][2 * BD];      // per-half (T1,T2) partials, 16.8 MB
__device__ float g_inv[OUT_N];
__device__ float g_part[16 * C2];
__device__ float g_colsum[C2];

// ---------------- kernel 1: per-row std (ddof=1) ----------------
__global__ void std_kernel(const float* __restrict__ spa,
                           const float* __restrict__ spe) {
    int row = blockIdx.x;                       // 0..2047
    const float* x = (row < B) ? (spa + row * D) : (spe + (row - B) * D);
    int t = threadIdx.x;                        // 64 threads = 1 wave
    float s = 0.0f, s2 = 0.0f;
    #pragma unroll
    for (int k = 0; k < D / 64; ++k) {
        float v = x[t + 64 * k];
        s += v;
        s2 += v * v;
    }
    #pragma unroll
    for (int off = 32; off > 0; off >>= 1) {
        s  += __shfl_down(s, off);
        s2 += __shfl_down(s2, off);
    }
    if (t == 0) {
        float var = (s2 - s * s * (1.0f / (float)D)) * (1.0f / (float)(D - 1));
        g_std[row] = sqrtf(fmaxf(var, 0.0f));
    }
}

// ---------------- kernel 2: pure PRNG, 4 elems/thread, p-halved ----------------
__global__ __launch_bounds__(256) void main_kernel(
        uint32_t kmA0, uint32_t kmA1, uint32_t knA0, uint32_t knA1,
        uint32_t kmB0, uint32_t kmB1, uint32_t knB0, uint32_t knB1) {
    // grid.x = 2048. bit10: feat, bit9: p-half, low 9 bits: idx block.
    int feat = (int)(blockIdx.x >> 10);                       // scalar
    int half = (int)((blockIdx.x >> 9) & 1u);                 // scalar
    int idx  = (int)((blockIdx.x & 511u) * 256u + threadIdx.x);  // [0, QBD)

    uint32_t km0 = feat ? kmB0 : kmA0;
    uint32_t km1 = feat ? kmB1 : kmA1;
    uint32_t kn0 = feat ? knB0 : knA0;
    uint32_t kn1 = feat ? knB1 : knA1;

    uint32_t jbase = (uint32_t)idx + (uint32_t)half * (NPERT / 2) * BD;
    float T1[4], T2[4];
    uint32_t j[4];
    #pragma unroll
    for (int e = 0; e < 4; ++e) {
        j[e]  = jbase + e * QBD;
        T1[e] = 0.0f;
        T2[e] = 0.0f;
    }

    #pragma unroll 1
    for (int p = 0; p < NPERT / 2; ++p) {
        uint32_t mb[4], nb[4];
        #pragma unroll
        for (int e = 0; e < 4; ++e) {
            mb[e] = pbits32(km0, km1, j[e]);
            nb[e] = pbits32(kn0, kn1, j[e]);
            j[e] += BD;
        }
        #pragma unroll
        for (int e = 0; e < 4; ++e) {
            float n = normal_from_bits(nb[e]);
            float g = (mb[e] < MASK_THR) ? n : 0.0f;
            T1[e] += g;
            T2[e] = fmaf(g, g, T2[e]);
        }
    }

    #pragma unroll
    for (int e = 0; e < 4; ++e) {
        g_pp[half][feat * BD + idx + e * QBD] = make_float2(T1[e], T2[e]);
    }
}

// ---------------- kernel 2b: combine halves + epilogue ----------------
__global__ void combine_kernel(const float* __restrict__ spa,
                               const float* __restrict__ spe,
                               float* __restrict__ out) {
    int elem = blockIdx.x * 256 + threadIdx.x;  // [0, 2*BD)
    int feat = elem >> 19;
    int rem  = elem & (BD - 1);
    float2 pa = g_pp[0][elem];
    float2 pb = g_pp[1][elem];
    float T1 = pa.x + pb.x;
    float T2 = pa.y + pb.y;
    const float* src = feat ? spe : spa;
    float x  = src[rem];
    float sd = g_std[feat * B + (rem >> 9)];
    float S   = 100.0f * x + sd * T1;
    float mu  = T1 * 0.01f;
    float var = sd * sd * (T2 * 0.01f - mu * mu) + 1e-6f;
    float inv = 1.0f / var;
    int o = (rem >> 9) * C2 + ((feat << 9) | (rem & (D - 1)));
    g_inv[o] = inv;
    out[o]   = inv * S;
}

// ---------------- kernel 3a/3b: deterministic column sum of 1/var ----------------
__global__ void colsum_part_kernel() {
    int c = blockIdx.x * 256 + threadIdx.x;     // grid.x = 4
    int grp = blockIdx.y;                       // grid.y = 16 (64 rows each)
    const float* base = g_inv + grp * 64 * C2 + c;
    float s = 0.0f;
    #pragma unroll 4
    for (int r = 0; r < 64; ++r) s += base[r * C2];
    g_part[grp * C2 + c] = s;
}

__global__ void colsum_fin_kernel() {
    int c = blockIdx.x * 256 + threadIdx.x;     // grid.x = 4
    float s = 0.0f;
    #pragma unroll
    for (int g = 0; g < 16; ++g) s += g_part[g * C2 + c];
    g_colsum[c] = s;
}

// ---------------- kernel 4: normalize ----------------
__global__ void finalize_kernel(float* __restrict__ out) {
    int i = blockIdx.x * 256 + threadIdx.x;
    out[i] = out[i] / g_colsum[i & (C2 - 1)];
}

// ---------------- launch ----------------
extern "C" void kernel_launch(void* const* d_in, const int* in_sizes, int n_in,
                              void* d_out, int out_size, void* d_ws, size_t ws_size,
                              hipStream_t stream) {
    const float* spa = (const float*)d_in[0];
    const float* spe = (const float*)d_in[1];
    float* out = (float*)d_out;

    // key(42) -> (0,42); partitionable fold-like splits.
    uint32_t spa0, spa1, spe0, spe1;
    host_child(0u, 42u, 0u, spa0, spa1);
    host_child(0u, 42u, 1u, spe0, spe1);
    uint32_t ka[4], kb[4];
    host_child(spa0, spa1, 0u, ka[0], ka[1]);   // km_spa
    host_child(spa0, spa1, 1u, ka[2], ka[3]);   // kn_spa
    host_child(spe0, spe1, 0u, kb[0], kb[1]);   // km_spe
    host_child(spe0, spe1, 1u, kb[2], kb[3]);   // kn_spe

    std_kernel<<<2 * B, 64, 0, stream>>>(spa, spe);

    main_kernel<<<2048, 256, 0, stream>>>(
        ka[0], ka[1], ka[2], ka[3],
        kb[0], kb[1], kb[2], kb[3]);

    combine_kernel<<<(2 * BD) / 256, 256, 0, stream>>>(spa, spe, out);

    dim3 pgrid(4, 16);
    colsum_part_kernel<<<pgrid, 256, 0, stream>>>();
    colsum_fin_kernel<<<4, 256, 0, stream>>>();
    finalize_kernel<<<OUT_N / 256, 256, 0, stream>>>(out);
}